// Round 12
// baseline (982.089 us; speedup 1.0000x reference)
//
#include <hip/hip_runtime.h>
#include <stdint.h>

#define T_LEN 2048
#define B_TOT 64
#define N_TAG 128
#define PAD 36  // dwords per LDS state row (32 + 4; keeps b128 16B-aligned)

typedef __attribute__((ext_vector_type(4))) float f32x4;
typedef __attribute__((ext_vector_type(4))) uint32_t u32x4;
typedef __attribute__((ext_vector_type(2))) uint32_t u32x2;
typedef __attribute__((ext_vector_type(2))) uint16_t u16x2;
typedef __attribute__((ext_vector_type(8))) int i32x8;

template <int S>
struct IC {
  static constexpr int value = S;
};

// pack two fp32 -> dword of two bf16 (round-half-up); elem0 in low half
__device__ __forceinline__ uint32_t pack2_bf16(float a, float b) {
  uint32_t ua = __float_as_uint(a) + 0x8000u;
  uint32_t ub = __float_as_uint(b) + 0x8000u;
  return __builtin_amdgcn_perm(ua, ub, 0x03020706u);
}
__device__ __forceinline__ float bf_lo(uint32_t w) {
  return __uint_as_float(w << 16);
}
__device__ __forceinline__ float bf_hi(uint32_t w) {
  return __uint_as_float(w & 0xffff0000u);
}
// pack 4 fp32 -> 4 fp8 e4m3 (OCP), bytes 0..3 = a,b,c,d
__device__ __forceinline__ uint32_t pack4_fp8(float a, float b, float c,
                                              float d) {
  int v = __builtin_amdgcn_cvt_pk_fp8_f32(a, b, 0, false);
  v = __builtin_amdgcn_cvt_pk_fp8_f32(c, d, v, true);
  return (uint32_t)v;
}
// pack 4 fp32 -> 4 bf8 e5m2 (OCP), bytes 0..3 = a,b,c,d
__device__ __forceinline__ uint32_t pack4_bf8(float a, float b, float c,
                                              float d) {
  int v = __builtin_amdgcn_cvt_pk_bf8_f32(a, b, 0, false);
  v = __builtin_amdgcn_cvt_pk_bf8_f32(c, d, v, true);
  return (uint32_t)v;
}
// per-u16 add (v_pk_add_u16): exact 2^-D on a packed bf16 pair via exponent
__device__ __forceinline__ uint32_t pkadd_u16(uint32_t a, uint32_t b) {
  u16x2 x = __builtin_bit_cast(u16x2, a);
  u16x2 y = __builtin_bit_cast(u16x2, b);
  x = x + y;
  return __builtin_bit_cast(uint32_t, x);
}

// Barrier draining ONLY lgkmcnt (LDS) -- global eem prefetches stay in
// flight across it; compiler inserts vmcnt before their use.
__device__ __forceinline__ void barrier_lds_only() {
  __asm__ volatile("s_waitcnt lgkmcnt(0)\n\ts_barrier" ::: "memory");
}

// prepass: ws[t][b][jperm] = bf16(exp(em[b][t][j])), with jperm swapping the
// (jt, q) 2-bit fields of j = [w:1][jt:2][q:2][r:2] so that a main-kernel
// lane's 16 values (fixed w,q; all jt,r) are CONTIGUOUS (2x dwordx4 load).
__global__ __launch_bounds__(256) void eem_prepass(const float* __restrict__ em,
                                                   uint32_t* __restrict__ ws) {
  const int tid = blockIdx.x * blockDim.x + threadIdx.x;  // 0 .. 2^21-1
  const int b = tid >> 15;
  const int rem = tid & 32767;
  const int t = rem >> 4;
  const int kk = rem & 15;  // 8 consecutive j per thread
  const float4* src =
      (const float4*)(em + ((size_t)b * T_LEN + t) * N_TAG + kk * 8);
  const float4 p0 = src[0];
  const float4 p1 = src[1];
  const uint32_t o0 = pack2_bf16(__expf(p0.x), __expf(p0.y));
  const uint32_t o1 = pack2_bf16(__expf(p0.z), __expf(p0.w));
  const uint32_t o2 = pack2_bf16(__expf(p1.x), __expf(p1.y));
  const uint32_t o3 = pack2_bf16(__expf(p1.z), __expf(p1.w));
  // j0 = 8kk: w=kk>>3, jt=(kk>>1)&3, q=(kk&1)*2; j0+4 bumps q's low bit (+16)
  const int wv_ = kk >> 3;
  const int q_ = (kk & 1) << 1;
  const int jt_ = (kk >> 1) & 3;
  const int djp = ((wv_ << 6) | (q_ << 4) | (jt_ << 2)) >> 1;  // dword index
  uint32_t* dst = ws + ((size_t)t * B_TOT + b) * 64 + djp;
  dst[0] = o0;
  dst[1] = o1;
  dst[8] = o2;
  dst[9] = o3;
}

// 4 blocks x 128 threads (2 waves), 16 batches/block. Wave w owns j in
// [64w, 64w+64) via FOUR INDEPENDENT mfma_scale_f32_16x16x128_f8f6f4 (A=E
// e4m3 per j-tile, B=bf8 state, unit scales -- validated in R11). Barrier
// couples only 2 waves (vs R8-R11's 8: minimal skew, the ~600cyc/step floor
// was the phase-locked 8-wave barrier). Rescale 2^-D applied EXACTLY on the
// packed bf16 eem via v_pk_add_u16 on exponent fields (8 ops, off the k_lds
// latency path). D (damped probe controller, R10) is double-buffered in LDS
// (removes the R10/R11 latent mid-step race). lgkmcnt-only barrier.
__global__ __launch_bounds__(128, 1) void crf_fwd_kernel(
    const float* __restrict__ em, const int* __restrict__ lens,
    const float* __restrict__ trans, const float* __restrict__ head,
    const float* __restrict__ last, const uint32_t* __restrict__ eem,
    float* __restrict__ out) {
  const int lane = threadIdx.x & 63;
  const int w = threadIdx.x >> 6;  // 0..1
  const int c = lane & 15;         // batch-in-tile (B/D col)
  const int q = lane >> 4;
  const int bg = (int)blockIdx.x * 16 + c;

  __shared__ uint32_t x_lds[2][16 * PAD];  // [pingpong][c*PAD + jgroup]
  __shared__ int k_lds[2][16];             // [pingpong][batch] scale exp D
  __shared__ float cap_lds[2][16];

  // A operands (fp8 e4m3), one per j-tile: A[m=c][k=q*32+pd*4+byte]
  //   = exp(trans[k][j]), j = 64w + 16jt + c
  i32x8 aop[4];
#pragma unroll
  for (int jt = 0; jt < 4; ++jt) {
    const int j = 64 * w + 16 * jt + c;
#pragma unroll
    for (int pd = 0; pd < 8; ++pd) {
      const int k0 = q * 32 + pd * 4;
      aop[jt][pd] = (int)pack4_fp8(__expf(trans[(k0 + 0) * N_TAG + j]),
                                   __expf(trans[(k0 + 1) * N_TAG + j]),
                                   __expf(trans[(k0 + 2) * N_TAG + j]),
                                   __expf(trans[(k0 + 3) * N_TAG + j]));
    }
  }

  // lane's 16 j's: j = 64w + 16jt + 4q + r
  float lastx[16];
#pragma unroll
  for (int jt = 0; jt < 4; ++jt)
#pragma unroll
    for (int r = 0; r < 4; ++r)
      lastx[4 * jt + r] = __expf(last[64 * w + 16 * jt + 4 * q + r]);

  const int len = lens[bg];
  float L = 0.f, Lcap = 0.f;

  // initial state: S0[b][j] = bf8(e^{head_j + em[b][0][j]})
  const float* emb = em + (size_t)bg * T_LEN * N_TAG;
  float v0[16];
#pragma unroll
  for (int jt = 0; jt < 4; ++jt) {
#pragma unroll
    for (int r = 0; r < 4; ++r) {
      const int j = 64 * w + 16 * jt + 4 * q + r;
      v0[4 * jt + r] = __expf(head[j] + emb[j]);
    }
    x_lds[0][c * PAD + 16 * w + 4 * jt + q] =
        pack4_bf8(v0[4 * jt], v0[4 * jt + 1], v0[4 * jt + 2], v0[4 * jt + 3]);
  }
  if (threadIdx.x < 16) {
    k_lds[0][threadIdx.x] = 3;
    k_lds[1][threadIdx.x] = 3;
  }
  if (len == 1) {  // edge (setup guarantees len>=1024; keep correct)
    float s = 0.f;
#pragma unroll
    for (int i = 0; i < 16; ++i) s += v0[i] * lastx[i];
    s += __shfl_xor(s, 16);
    s += __shfl_xor(s, 32);
    if (q == 0) cap_lds[w][c] = s;
  }
  __syncthreads();
  if (len == 1 && w == 0 && lane < 16)
    out[bg] = __logf(cap_lds[0][c] + cap_lds[1][c]);

  // eem prefetch: slot t&3 holds row t, this lane's 16 bf16 (contiguous)
  u32x4 eslotA[4], eslotB[4];
  auto issue_eem = [&](auto sc, int row) {
    constexpr int S = decltype(sc)::value;
    const uint32_t* p =
        eem + ((size_t)row * B_TOT + bg) * 64 + 32 * w + 8 * q;
    eslotA[S] = *(const u32x4*)p;
    eslotB[S] = *(const u32x4*)(p + 4);
  };
  issue_eem(IC<1>{}, 1);
  issue_eem(IC<2>{}, 2);
  issue_eem(IC<3>{}, 3);

  const f32x4 vzero = {0.f, 0.f, 0.f, 0.f};

  auto step = [&](auto slotc, int t) {
    constexpr int SLOT = decltype(slotc)::value;
    constexpr int RP = (SLOT + 1) & 1;  // read buffer (state of t-1)
    constexpr int WP = SLOT & 1;        // write buffer
    {
      int row = t + 3;
      if (row > T_LEN - 1) row = T_LEN - 1;
      issue_eem(IC<(SLOT + 3) & 3>{}, row);
    }
    const int D = k_lds[RP][c];  // damped probe exponent (1-step lag)
    // B operand: full k=128 bf8 state, 2x ds_read_b128
    const u32x4 s0 = *(const u32x4*)&x_lds[RP][c * PAD + 8 * q];
    const u32x4 s1 = *(const u32x4*)&x_lds[RP][c * PAD + 8 * q + 4];
    // exact 2^-D on packed bf16 (exponent-field add; no overflow by range)
    const uint32_t hh = ((uint32_t)(-D) << 7) & 0xffffu;
    const uint32_t dadd = hh * 0x00010001u;
    uint32_t evs[8];
#pragma unroll
    for (int k = 0; k < 4; ++k) evs[k] = pkadd_u16(eslotA[SLOT][k], dadd);
#pragma unroll
    for (int k = 0; k < 4; ++k) evs[4 + k] = pkadd_u16(eslotB[SLOT][k], dadd);
    L += (float)D * 0.6931471805599453f;
    i32x8 bop;
    bop[0] = (int)s0[0];
    bop[1] = (int)s0[1];
    bop[2] = (int)s0[2];
    bop[3] = (int)s0[3];
    bop[4] = (int)s1[0];
    bop[5] = (int)s1[1];
    bop[6] = (int)s1[2];
    bop[7] = (int)s1[3];
    // 4 INDEPENDENT K=128 MX MFMAs (unit scales; validated R11)
    f32x4 acc[4];
#pragma unroll
    for (int jt = 0; jt < 4; ++jt)
      acc[jt] = __builtin_amdgcn_mfma_scale_f32_16x16x128_f8f6f4(
          aop[jt], bop, vzero, 0, 1, 0, 0x7f7f7f7f, 0, 0x7f7f7f7f);
    // st = acc * eem*2^-D  (evs order: jperm -> index 4jt+r)
    float st[16];
#pragma unroll
    for (int jt = 0; jt < 4; ++jt) {
      st[4 * jt + 0] = acc[jt][0] * bf_lo(evs[2 * jt]);
      st[4 * jt + 1] = acc[jt][1] * bf_hi(evs[2 * jt]);
      st[4 * jt + 2] = acc[jt][2] * bf_lo(evs[2 * jt + 1]);
      st[4 * jt + 3] = acc[jt][3] * bf_hi(evs[2 * jt + 1]);
    }
    // capture: out_b = log(sum_j st * e^{last}) + L
    if (t == len - 1) {
      float s = 0.f;
#pragma unroll
      for (int i = 0; i < 16; ++i) s += st[i] * lastx[i];
      s += __shfl_xor(s, 16);
      s += __shfl_xor(s, 32);
      if (q == 0) cap_lds[w][c] = s;
      Lcap = L;
    }
    // damped probe of j=0 (wave 0, lanes 0-15: q=0, tile 0, r=0)
    if (w == 0 && lane < 16) {
      int e = (int)(__float_as_uint(acc[0][0]) >> 23) - 127;
      e = e < -40 ? -40 : (e > 40 ? 40 : e);
      k_lds[WP][c] = (e >> 1) + 3;  // half-gain: z^2 = z - 1/2, damped
    }
    // clamp (bf8-safe) and store state (4 b32, 2-way banks = free)
#pragma unroll
    for (int jt = 0; jt < 4; ++jt) {
      x_lds[WP][c * PAD + 16 * w + 4 * jt + q] =
          pack4_bf8(fminf(st[4 * jt + 0], 16384.f),
                    fminf(st[4 * jt + 1], 16384.f),
                    fminf(st[4 * jt + 2], 16384.f),
                    fminf(st[4 * jt + 3], 16384.f));
    }
    barrier_lds_only();
    if (t == len - 1 && w == 0 && lane < 16)
      out[bg] = __logf(cap_lds[0][c] + cap_lds[1][c]) + Lcap;
  };

  int t = 1;
#pragma unroll 1
  for (int it = 0; it < 511; ++it) {  // t = 1 .. 2044
    step(IC<1>{}, t);
    step(IC<2>{}, t + 1);
    step(IC<3>{}, t + 2);
    step(IC<0>{}, t + 3);
    t += 4;
  }
  step(IC<1>{}, t);      // 2045
  step(IC<2>{}, t + 1);  // 2046
  step(IC<3>{}, t + 2);  // 2047
}

extern "C" void kernel_launch(void* const* d_in, const int* in_sizes, int n_in,
                              void* d_out, int out_size, void* d_ws,
                              size_t ws_size, hipStream_t stream) {
  const float* em = (const float*)d_in[0];
  const int* lens = (const int*)d_in[1];
  const float* trans = (const float*)d_in[2];
  const float* head = (const float*)d_in[3];
  const float* last = (const float*)d_in[4];
  float* out = (float*)d_out;
  uint32_t* ws = (uint32_t*)d_ws;  // 2048*64*128 bf16 = 32 MiB

  eem_prepass<<<8192, 256, 0, stream>>>(em, ws);
  crf_fwd_kernel<<<4, 128, 0, stream>>>(em, lens, trans, head, last, ws, out);
}